// Round 4
// baseline (926.729 us; speedup 1.0000x reference)
//
#include <hip/hip_runtime.h>
#include <hip/hip_bf16.h>

#define TT 24
#define FF 16
#define HH 64
#define GG 192   // 3*HH

typedef __attribute__((ext_vector_type(4))) float f32x4;
typedef __attribute__((ext_vector_type(8))) short s16x8;

__device__ __forceinline__ ushort f2bf(float x){
  union{float f; unsigned u;} c; c.f = x;
  unsigned r = (c.u + 0x7fffu + ((c.u>>16)&1u)) >> 16;
  return (ushort)r;
}
__device__ __forceinline__ float bf2f(ushort h){
  union{unsigned u; float f;} c; c.u = ((unsigned)h)<<16; return c.f;
}
__device__ __forceinline__ float fast_rcp(float x){ return __builtin_amdgcn_rcpf(x); }
__device__ __forceinline__ float sigmoid_f(float x){
  return fast_rcp(1.0f + __expf(-x));
}
__device__ __forceinline__ float tanh_f(float x){
  float e = __expf(-2.0f * fabsf(x));
  float th = (1.0f - e) * fast_rcp(1.0f + e);
  return copysignf(th, x);
}

// ---------------- CSR build ----------------
__global__ void k_zero(int* __restrict__ p, long n){
  long i = (long)blockIdx.x*blockDim.x + threadIdx.x;
  long st = (long)gridDim.x*blockDim.x;
  for(; i<n; i+=st) p[i]=0;
}

__global__ void k_deg(const int* __restrict__ ei, int E, int* __restrict__ deg){
  int i = blockIdx.x*blockDim.x + threadIdx.x;
  if(i<E) atomicAdd(&deg[ei[E+i]], 1);   // dst = ei[E+i]
}

__global__ void k_dinv(const int* __restrict__ deg, float* __restrict__ dinv, int N){
  int i = blockIdx.x*blockDim.x + threadIdx.x;
  if(i<N) dinv[i] = rsqrtf((float)deg[i] + 1.0f);
}

__global__ __launch_bounds__(1024) void k_scan(const int* __restrict__ deg, int* __restrict__ offsets, int N){
  __shared__ int s[1024];
  int tid = threadIdx.x;
  int CH = (N + 1023) >> 10;
  int lo = tid*CH, hi = min(N, lo+CH);
  int sum=0;
  for(int j=lo;j<hi;j++) sum += deg[j];
  s[tid]=sum; __syncthreads();
  for(int o=1;o<1024;o<<=1){
    int v = 0;
    if(tid>=o) v = s[tid-o];
    __syncthreads();
    s[tid] += v;
    __syncthreads();
  }
  int run = s[tid]-sum;
  for(int j=lo;j<hi;j++){ offsets[j]=run; run += deg[j]; }
  if(tid==1023) offsets[N]=s[1023];
}

__global__ void k_fill(const int* __restrict__ ei, int E, const float* __restrict__ dinv,
                       const int* __restrict__ offsets, int* __restrict__ counters,
                       int2* __restrict__ csr2){
  int i = blockIdx.x*blockDim.x + threadIdx.x;
  if(i>=E) return;
  int s = ei[i], d = ei[E+i];
  int slot = offsets[d] + atomicAdd(&counters[d], 1);
  csr2[slot] = make_int2(s, __float_as_int(dinv[s]*dinv[d]));
}

// ---------------- weight prep ----------------
__global__ void k_m1(const float* __restrict__ gcn_w, const float* __restrict__ gcn_b,
                     const float* __restrict__ w_ih, const float* __restrict__ b_ih,
                     ushort* __restrict__ m1H, ushort* __restrict__ m1L, float* __restrict__ c1){
  int tid = blockIdx.x*blockDim.x + threadIdx.x;
  if(tid < GG*FF){
    int j = tid >> 4, f = tid & 15;
    float s = 0.f;
    for(int k=0;k<HH;k++) s += gcn_w[f*HH+k]*w_ih[j*HH+k];
    ushort h = f2bf(s);
    m1H[tid] = h;
    m1L[tid] = f2bf(s - bf2f(h));
  } else if (tid < GG*FF + GG){
    int j = tid - GG*FF;
    float s = b_ih[j];
    for(int k=0;k<HH;k++) s += gcn_b[k]*w_ih[j*HH+k];
    c1[j] = s;
  }
}

__global__ void k_split(const float* __restrict__ w, ushort* __restrict__ wH, ushort* __restrict__ wL, int n){
  int i = blockIdx.x*blockDim.x + threadIdx.x;
  if(i<n){
    float v = w[i];
    ushort h = f2bf(v);
    wH[i] = h;
    wL[i] = f2bf(v - bf2f(h));
  }
}

// ---------------- aggregation v4: 4 t per wave in-lane, 2-round reduce ----------------
// grid = 6 tgroups (outer) * NC chunks; block = 1024 = 16 waves = 16 nodes.
// lane: e = l&3 (4 edge slots), f4 = (l>>2)&3 (float4 slice), tl = l>>4 (t within group).
// Per csr entry: broadcast to 16 lanes (4 t * 4 f4); each lane 1 gather + 4 FMA.
// 2-way predicated unroll -> 8 edges per wave-round. Reduce = 2 shfl rounds.
__global__ __launch_bounds__(1024)
void k_agg4(const float* __restrict__ x, const int* __restrict__ offsets,
            const int2* __restrict__ csr2, const float* __restrict__ dinv,
            ushort* __restrict__ aggH, ushort* __restrict__ aggL,
            int N, int NC){
  int bid = blockIdx.x;
  int tg = bid / NC, chunk = bid - tg*NC;
  int wv = threadIdx.x >> 6, l = threadIdx.x & 63;
  int n = chunk*16 + wv;
  if(n >= N) return;
  int e = l & 3, f4 = (l >> 2) & 3, tl = l >> 4;
  int t = tg*4 + tl;
  const int N4 = N*4;
  const float4* xb = (const float4*)x;
  const int vbase = t*N4 + f4;           // per-lane constant part of gather index

  float4 a = make_float4(0.f,0.f,0.f,0.f);
  int lo = offsets[n], hi = offsets[n+1];
  for(int j = lo + e; j < hi; j += 8){
    int j1 = j + 4;
    bool ok = j1 < hi;
    int2 c0 = csr2[j];
    int2 c1 = csr2[ok ? j1 : j];
    float4 v0 = xb[vbase + c0.x*4];
    float4 v1 = xb[vbase + c1.x*4];
    float w0 = __int_as_float(c0.y);
    float w1 = ok ? __int_as_float(c1.y) : 0.f;
    a.x += w0*v0.x; a.y += w0*v0.y; a.z += w0*v0.z; a.w += w0*v0.w;
    a.x += w1*v1.x; a.y += w1*v1.y; a.z += w1*v1.z; a.w += w1*v1.w;
  }
  // reduce over e (4 slots)
  #pragma unroll
  for(int m = 1; m <= 2; m <<= 1){
    a.x += __shfl_xor(a.x, m, 64);
    a.y += __shfl_xor(a.y, m, 64);
    a.z += __shfl_xor(a.z, m, 64);
    a.w += __shfl_xor(a.w, m, 64);
  }
  if(e == 0){
    float sn = dinv[n]; sn *= sn;
    float4 xs = xb[vbase + n*4];
    a.x += sn*xs.x; a.y += sn*xs.y; a.z += sn*xs.z; a.w += sn*xs.w;
    size_t o = ((size_t)t*N + n)*FF + f4*4;
    ushort4 h, lw;
    h.x = f2bf(a.x); lw.x = f2bf(a.x - bf2f(h.x));
    h.y = f2bf(a.y); lw.y = f2bf(a.y - bf2f(h.y));
    h.z = f2bf(a.z); lw.z = f2bf(a.z - bf2f(h.z));
    h.w = f2bf(a.w); lw.w = f2bf(a.w - bf2f(h.w));
    *(ushort4*)(aggH + o) = h;
    *(ushort4*)(aggL + o) = lw;
  }
}

// ---------------- persistent MFMA GRU over all 24 steps + fused linear head ----------------
__global__ __launch_bounds__(256, 2)
void k_gru_all(const ushort* __restrict__ aggH, const ushort* __restrict__ aggL,
               const ushort* __restrict__ whhH, const ushort* __restrict__ whhL,
               const ushort* __restrict__ m1H,  const ushort* __restrict__ m1L,
               const float* __restrict__ c1, const float* __restrict__ bhh,
               const float* __restrict__ lin_w, const float* __restrict__ lin_b,
               float* __restrict__ out, int N, int P){
  __shared__ __align__(16) ushort hb[2][2][64*64];   // [buf][hi/lo][node*64+ch] swizzled
  const int tid  = threadIdx.x;
  const int l    = tid & 63, w = tid >> 6;
  const int lrow = l & 15;
  const int lgrp = l >> 4;
  const int ch   = w*16 + lrow;
  const int nbase = blockIdx.x * 64;

  s16x8 bH[3][2], bL[3][2], mHf[3], mLf[3];
  #pragma unroll
  for(int g=0; g<3; g++){
    int j = g*HH + w*16 + lrow;
    #pragma unroll
    for(int ks=0; ks<2; ks++){
      int k0 = ks*32 + lgrp*8;
      bH[g][ks] = *(const s16x8*)(whhH + j*HH + k0);
      bL[g][ks] = *(const s16x8*)(whhL + j*HH + k0);
    }
    if(lgrp < 2){
      int k0 = lgrp*8;
      mHf[g] = *(const s16x8*)(m1H + j*FF + k0);
      mLf[g] = *(const s16x8*)(m1L + j*FF + k0);
    } else {
      mHf[g] = (s16x8){0,0,0,0,0,0,0,0};
      mLf[g] = (s16x8){0,0,0,0,0,0,0,0};
    }
  }

  const float cbr = c1[ch]      + bhh[ch];
  const float cbz = c1[ch+HH]   + bhh[ch+HH];
  const float c1n = c1[ch+2*HH];
  const float bhn = bhh[ch+2*HH];

  float hreg[16];
  #pragma unroll
  for(int i=0;i<16;i++) hreg[i]=0.f;

  {
    uint* p = (uint*)&hb[0][0][0];
    for(int i=tid; i<4096; i+=256) p[i]=0u;
  }
  __syncthreads();

  for(int t=0; t<TT; t++){
    const int cur = t & 1, nxt = cur ^ 1;
    const ushort* aHt = aggH + (size_t)t*N*FF;
    const ushort* aLt = aggL + (size_t)t*N*FF;

    #pragma unroll
    for(int nt=0; nt<4; nt++){
      s16x8 ahH[2], ahL[2];
      const int r = nt*16 + lrow;
      #pragma unroll
      for(int ks=0; ks<2; ks++){
        int idx = (r*64 + ks*32 + lgrp*8) ^ ((r&7)<<3);
        ahH[ks] = *(const s16x8*)&hb[cur][0][idx];
        ahL[ks] = *(const s16x8*)&hb[cur][1][idx];
      }
      s16x8 agHf = (s16x8){0,0,0,0,0,0,0,0};
      s16x8 agLf = (s16x8){0,0,0,0,0,0,0,0};
      {
        int node = nbase + nt*16 + lrow;
        int nodec = min(node, N-1);
        if(lgrp < 2){
          size_t o = (size_t)nodec*FF + lgrp*8;
          agHf = *(const s16x8*)(aHt + o);
          agLf = *(const s16x8*)(aLt + o);
        }
      }

      f32x4 aR = {0.f,0.f,0.f,0.f}, aZ = {0.f,0.f,0.f,0.f};
      f32x4 aNi= {0.f,0.f,0.f,0.f}, aNh= {0.f,0.f,0.f,0.f};
      #pragma unroll
      for(int ks=0; ks<2; ks++){
        aR = __builtin_amdgcn_mfma_f32_16x16x32_bf16(ahH[ks], bH[0][ks], aR, 0,0,0);
        aR = __builtin_amdgcn_mfma_f32_16x16x32_bf16(ahL[ks], bH[0][ks], aR, 0,0,0);
        aR = __builtin_amdgcn_mfma_f32_16x16x32_bf16(ahH[ks], bL[0][ks], aR, 0,0,0);
        aZ = __builtin_amdgcn_mfma_f32_16x16x32_bf16(ahH[ks], bH[1][ks], aZ, 0,0,0);
        aZ = __builtin_amdgcn_mfma_f32_16x16x32_bf16(ahL[ks], bH[1][ks], aZ, 0,0,0);
        aZ = __builtin_amdgcn_mfma_f32_16x16x32_bf16(ahH[ks], bL[1][ks], aZ, 0,0,0);
        aNh= __builtin_amdgcn_mfma_f32_16x16x32_bf16(ahH[ks], bH[2][ks], aNh,0,0,0);
        aNh= __builtin_amdgcn_mfma_f32_16x16x32_bf16(ahL[ks], bH[2][ks], aNh,0,0,0);
        aNh= __builtin_amdgcn_mfma_f32_16x16x32_bf16(ahH[ks], bL[2][ks], aNh,0,0,0);
      }
      aR  = __builtin_amdgcn_mfma_f32_16x16x32_bf16(agHf, mHf[0], aR, 0,0,0);
      aR  = __builtin_amdgcn_mfma_f32_16x16x32_bf16(agLf, mHf[0], aR, 0,0,0);
      aR  = __builtin_amdgcn_mfma_f32_16x16x32_bf16(agHf, mLf[0], aR, 0,0,0);
      aZ  = __builtin_amdgcn_mfma_f32_16x16x32_bf16(agHf, mHf[1], aZ, 0,0,0);
      aZ  = __builtin_amdgcn_mfma_f32_16x16x32_bf16(agLf, mHf[1], aZ, 0,0,0);
      aZ  = __builtin_amdgcn_mfma_f32_16x16x32_bf16(agHf, mLf[1], aZ, 0,0,0);
      aNi = __builtin_amdgcn_mfma_f32_16x16x32_bf16(agHf, mHf[2], aNi,0,0,0);
      aNi = __builtin_amdgcn_mfma_f32_16x16x32_bf16(agLf, mHf[2], aNi,0,0,0);
      aNi = __builtin_amdgcn_mfma_f32_16x16x32_bf16(agHf, mLf[2], aNi,0,0,0);

      #pragma unroll
      for(int i=0;i<4;i++){
        float r_ = sigmoid_f(aR[i] + cbr);
        float z_ = sigmoid_f(aZ[i] + cbz);
        float nn = tanh_f(aNi[i] + c1n + r_*(aNh[i] + bhn));
        int hidx = nt*4 + i;
        float hp = hreg[hidx];
        float hn = nn + z_*(hp - nn);
        hreg[hidx] = hn;
        int noderow = nt*16 + lgrp*4 + i;
        int idx = (noderow*64 + ch) ^ ((noderow&7)<<3);
        ushort hiw = f2bf(hn);
        hb[nxt][0][idx] = hiw;
        hb[nxt][1][idx] = f2bf(hn - bf2f(hiw));
      }
    }
    __syncthreads();
  }

  // ---- fused linear head ----
  // stage h (fp32) into LDS: 64 nodes x 64 ch
  float* hs = (float*)&hb[0][0][0];
  #pragma unroll
  for(int hidx=0; hidx<16; hidx++){
    int nt = hidx >> 2, i = hidx & 3;
    int r = nt*16 + lgrp*4 + i;
    hs[r*64 + ch] = hreg[hidx];
  }
  __syncthreads();
  // thread layout: r = l (node in block), wave w handles p = w, w+4, ...
  {
    int r = l;
    int node = nbase + r;
    if(node < N){
      float hv[HH];
      #pragma unroll
      for(int q=0;q<16;q++){
        float4 v = *(const float4*)&hs[r*64 + q*4];
        hv[4*q]=v.x; hv[4*q+1]=v.y; hv[4*q+2]=v.z; hv[4*q+3]=v.w;
      }
      for(int p=w; p<P; p+=4){
        float acc = lin_b[p];
        #pragma unroll
        for(int k=0;k<HH;k++) acc += hv[k]*lin_w[p*HH+k];
        out[(size_t)p*N + node] = acc;
      }
    }
  }
}

extern "C" void kernel_launch(void* const* d_in, const int* in_sizes, int n_in,
                              void* d_out, int out_size, void* d_ws, size_t ws_size,
                              hipStream_t stream){
  const float* x     = (const float*)d_in[0];
  const float* gcn_w = (const float*)d_in[2];
  const float* gcn_b = (const float*)d_in[3];
  const float* w_ih  = (const float*)d_in[4];
  const float* w_hh  = (const float*)d_in[5];
  const float* b_ih  = (const float*)d_in[6];
  const float* b_hh  = (const float*)d_in[7];
  const float* lin_w = (const float*)d_in[8];
  const float* lin_b = (const float*)d_in[9];
  const int*   ei    = (const int*)d_in[10];
  const int E = in_sizes[10]/2;
  const int N = in_sizes[0]/(TT*FF);
  const int P = in_sizes[9];

  char* wsp = (char*)d_ws;
  auto alloc = [&](size_t bytes)->void*{ void* p = wsp; wsp += (bytes + 255) & ~(size_t)255; return p; };
  int*    deg      = (int*)   alloc((size_t)N*4);
  int*    counters = (int*)   alloc((size_t)N*4);
  int*    offsets  = (int*)   alloc((size_t)(N+1)*4);
  float*  dinv     = (float*) alloc((size_t)N*4);
  int2*   csr2     = (int2*)  alloc((size_t)E*8);
  ushort* aggH     = (ushort*)alloc((size_t)TT*N*FF*2);
  ushort* aggL     = (ushort*)alloc((size_t)TT*N*FF*2);
  ushort* m1H      = (ushort*)alloc((size_t)GG*FF*2);
  ushort* m1L      = (ushort*)alloc((size_t)GG*FF*2);
  float*  c1       = (float*) alloc((size_t)GG*4);
  ushort* whhH     = (ushort*)alloc((size_t)GG*HH*2);
  ushort* whhL     = (ushort*)alloc((size_t)GG*HH*2);

  k_zero<<<(N+255)/256, 256, 0, stream>>>(deg, N);
  k_zero<<<(N+255)/256, 256, 0, stream>>>(counters, N);

  k_deg <<<(E+255)/256, 256, 0, stream>>>(ei, E, deg);
  k_dinv<<<(N+255)/256, 256, 0, stream>>>(deg, dinv, N);
  k_scan<<<1, 1024, 0, stream>>>(deg, offsets, N);
  k_fill<<<(E+255)/256, 256, 0, stream>>>(ei, E, dinv, offsets, counters, csr2);
  k_m1  <<<(GG*FF+GG+255)/256, 256, 0, stream>>>(gcn_w, gcn_b, w_ih, b_ih, m1H, m1L, c1);
  k_split<<<(GG*HH+255)/256, 256, 0, stream>>>(w_hh, whhH, whhL, GG*HH);

  const int NC = (N + 15) / 16;
  k_agg4<<<6*NC, 1024, 0, stream>>>(x, offsets, csr2, dinv, aggH, aggL, N, NC);

  k_gru_all<<<(N+63)/64, 256, 0, stream>>>(aggH, aggL, whhH, whhL, m1H, m1L, c1, b_hh,
                                           lin_w, lin_b, (float*)d_out, N, P);
}

// Round 5
// 828.494 us; speedup vs baseline: 1.1186x; 1.1186x over previous
//
#include <hip/hip_runtime.h>
#include <hip/hip_bf16.h>

#define TT 24
#define FF 16
#define HH 64
#define GG 192   // 3*HH

typedef __attribute__((ext_vector_type(4))) float f32x4;
typedef __attribute__((ext_vector_type(8))) short s16x8;

__device__ __forceinline__ ushort f2bf(float x){
  union{float f; unsigned u;} c; c.f = x;
  unsigned r = (c.u + 0x7fffu + ((c.u>>16)&1u)) >> 16;
  return (ushort)r;
}
__device__ __forceinline__ float bf2f(ushort h){
  union{unsigned u; float f;} c; c.u = ((unsigned)h)<<16; return c.f;
}
__device__ __forceinline__ float fast_rcp(float x){ return __builtin_amdgcn_rcpf(x); }
__device__ __forceinline__ float sigmoid_f(float x){
  return fast_rcp(1.0f + __expf(-x));
}
__device__ __forceinline__ float tanh_f(float x){
  float e = __expf(-2.0f * fabsf(x));
  float th = (1.0f - e) * fast_rcp(1.0f + e);
  return copysignf(th, x);
}

// ---------------- CSR build ----------------
__global__ void k_zero(int* __restrict__ p, long n){
  long i = (long)blockIdx.x*blockDim.x + threadIdx.x;
  long st = (long)gridDim.x*blockDim.x;
  for(; i<n; i+=st) p[i]=0;
}

__global__ void k_deg(const int* __restrict__ ei, int E, int* __restrict__ deg){
  int i = blockIdx.x*blockDim.x + threadIdx.x;
  if(i<E) atomicAdd(&deg[ei[E+i]], 1);   // dst = ei[E+i]
}

__global__ void k_dinv(const int* __restrict__ deg, float* __restrict__ dinv, int N){
  int i = blockIdx.x*blockDim.x + threadIdx.x;
  if(i<N) dinv[i] = rsqrtf((float)deg[i] + 1.0f);
}

__global__ __launch_bounds__(1024) void k_scan(const int* __restrict__ deg, int* __restrict__ offsets, int N){
  __shared__ int s[1024];
  int tid = threadIdx.x;
  int CH = (N + 1023) >> 10;
  int lo = tid*CH, hi = min(N, lo+CH);
  int sum=0;
  for(int j=lo;j<hi;j++) sum += deg[j];
  s[tid]=sum; __syncthreads();
  for(int o=1;o<1024;o<<=1){
    int v = 0;
    if(tid>=o) v = s[tid-o];
    __syncthreads();
    s[tid] += v;
    __syncthreads();
  }
  int run = s[tid]-sum;
  for(int j=lo;j<hi;j++){ offsets[j]=run; run += deg[j]; }
  if(tid==1023) offsets[N]=s[1023];
}

__global__ void k_fill(const int* __restrict__ ei, int E, const float* __restrict__ dinv,
                       const int* __restrict__ offsets, int* __restrict__ counters,
                       int2* __restrict__ csr2){
  int i = blockIdx.x*blockDim.x + threadIdx.x;
  if(i>=E) return;
  int s = ei[i], d = ei[E+i];
  int slot = offsets[d] + atomicAdd(&counters[d], 1);
  csr2[slot] = make_int2(s, __float_as_int(dinv[s]*dinv[d]));
}

// ---------------- weight prep ----------------
__global__ void k_m1(const float* __restrict__ gcn_w, const float* __restrict__ gcn_b,
                     const float* __restrict__ w_ih, const float* __restrict__ b_ih,
                     ushort* __restrict__ m1H, ushort* __restrict__ m1L, float* __restrict__ c1){
  int tid = blockIdx.x*blockDim.x + threadIdx.x;
  if(tid < GG*FF){
    int j = tid >> 4, f = tid & 15;
    float s = 0.f;
    for(int k=0;k<HH;k++) s += gcn_w[f*HH+k]*w_ih[j*HH+k];
    ushort h = f2bf(s);
    m1H[tid] = h;
    m1L[tid] = f2bf(s - bf2f(h));
  } else if (tid < GG*FF + GG){
    int j = tid - GG*FF;
    float s = b_ih[j];
    for(int k=0;k<HH;k++) s += gcn_b[k]*w_ih[j*HH+k];
    c1[j] = s;
  }
}

__global__ void k_split(const float* __restrict__ w, ushort* __restrict__ wH, ushort* __restrict__ wL, int n){
  int i = blockIdx.x*blockDim.x + threadIdx.x;
  if(i<n){
    float v = w[i];
    ushort h = f2bf(v);
    wH[i] = h;
    wL[i] = f2bf(v - bf2f(h));
  }
}

// ---------------- transpose x: [t][n][f4] -> xT[n][t][f4] (float4 units) ----------------
__global__ void k_xt(const float4* __restrict__ x4, float4* __restrict__ xT, int N){
  int i = blockIdx.x*blockDim.x + threadIdx.x;
  int total = TT*N*4;
  if(i >= total) return;
  int t = i / (N*4);
  int r = i - t*(N*4);
  int n = r >> 2, f4 = r & 3;
  xT[(size_t)n*96 + t*4 + f4] = x4[i];
}

// ---------------- aggregation v5: wave per dst node, all 24 t at once ----------------
// xT row per node = 96 float4 (24 t x 4 f4), contiguous 1536 B.
// lane: half = l>>5 (edge slot), lh = l&31 (position slice). Each half-wave reads one
// edge's full row as 3 coalesced float4 loads (positions lh, lh+32, lh+64).
// 2x unroll -> 4 edges / iteration, 6 gathers in flight per lane.
__global__ __launch_bounds__(256)
void k_aggT(const float4* __restrict__ xT, const int* __restrict__ offsets,
            const int2* __restrict__ csr2, const float* __restrict__ dinv,
            ushort* __restrict__ aggH, ushort* __restrict__ aggL, int N){
  int wid = (blockIdx.x*blockDim.x + threadIdx.x) >> 6;
  if(wid >= N) return;
  const int l = threadIdx.x & 63;
  const int half = l >> 5, lh = l & 31;
  const int n = wid;

  float4 a0 = make_float4(0.f,0.f,0.f,0.f);
  float4 a1 = make_float4(0.f,0.f,0.f,0.f);
  float4 a2 = make_float4(0.f,0.f,0.f,0.f);

  const int lo = offsets[n], hi = offsets[n+1];
  for(int j = lo; j < hi; j += 4){
    int ja = j + half;
    int jb = j + 2 + half;
    bool okA = ja < hi, okB = jb < hi;
    int2 cA = csr2[okA ? ja : lo];
    int2 cB = csr2[okB ? jb : lo];
    float wA = okA ? __int_as_float(cA.y) : 0.f;
    float wB = okB ? __int_as_float(cB.y) : 0.f;
    const float4* rA = xT + (size_t)cA.x*96 + lh;
    const float4* rB = xT + (size_t)cB.x*96 + lh;
    float4 vA0 = rA[0], vA1 = rA[32], vA2 = rA[64];
    float4 vB0 = rB[0], vB1 = rB[32], vB2 = rB[64];
    a0.x += wA*vA0.x; a0.y += wA*vA0.y; a0.z += wA*vA0.z; a0.w += wA*vA0.w;
    a1.x += wA*vA1.x; a1.y += wA*vA1.y; a1.z += wA*vA1.z; a1.w += wA*vA1.w;
    a2.x += wA*vA2.x; a2.y += wA*vA2.y; a2.z += wA*vA2.z; a2.w += wA*vA2.w;
    a0.x += wB*vB0.x; a0.y += wB*vB0.y; a0.z += wB*vB0.z; a0.w += wB*vB0.w;
    a1.x += wB*vB1.x; a1.y += wB*vB1.y; a1.z += wB*vB1.z; a1.w += wB*vB1.w;
    a2.x += wB*vB2.x; a2.y += wB*vB2.y; a2.z += wB*vB2.z; a2.w += wB*vB2.w;
  }
  // reduce across the two halves (lanes l <-> l^32 hold same positions)
  a0.x += __shfl_xor(a0.x, 32, 64); a0.y += __shfl_xor(a0.y, 32, 64);
  a0.z += __shfl_xor(a0.z, 32, 64); a0.w += __shfl_xor(a0.w, 32, 64);
  a1.x += __shfl_xor(a1.x, 32, 64); a1.y += __shfl_xor(a1.y, 32, 64);
  a1.z += __shfl_xor(a1.z, 32, 64); a1.w += __shfl_xor(a1.w, 32, 64);
  a2.x += __shfl_xor(a2.x, 32, 64); a2.y += __shfl_xor(a2.y, 32, 64);
  a2.z += __shfl_xor(a2.z, 32, 64); a2.w += __shfl_xor(a2.w, 32, 64);

  if(half == 0){
    float sn = dinv[n]; sn *= sn;
    const float4* rS = xT + (size_t)n*96 + lh;
    float4 s0 = rS[0], s1 = rS[32], s2 = rS[64];
    a0.x += sn*s0.x; a0.y += sn*s0.y; a0.z += sn*s0.z; a0.w += sn*s0.w;
    a1.x += sn*s1.x; a1.y += sn*s1.y; a1.z += sn*s1.z; a1.w += sn*s1.w;
    a2.x += sn*s2.x; a2.y += sn*s2.y; a2.z += sn*s2.z; a2.w += sn*s2.w;
    float4 acc[3] = {a0, a1, a2};
    #pragma unroll
    for(int k=0;k<3;k++){
      int p  = lh + k*32;          // p = t*4 + f4
      int t  = p >> 2, f4 = p & 3;
      size_t o = ((size_t)t*N + n)*FF + f4*4;
      float4 a = acc[k];
      ushort4 h, lw;
      h.x = f2bf(a.x); lw.x = f2bf(a.x - bf2f(h.x));
      h.y = f2bf(a.y); lw.y = f2bf(a.y - bf2f(h.y));
      h.z = f2bf(a.z); lw.z = f2bf(a.z - bf2f(h.z));
      h.w = f2bf(a.w); lw.w = f2bf(a.w - bf2f(h.w));
      *(ushort4*)(aggH + o) = h;
      *(ushort4*)(aggL + o) = lw;
    }
  }
}

// ---------------- persistent MFMA GRU over all 24 steps + fused linear head ----------------
__global__ __launch_bounds__(256, 2)
void k_gru_all(const ushort* __restrict__ aggH, const ushort* __restrict__ aggL,
               const ushort* __restrict__ whhH, const ushort* __restrict__ whhL,
               const ushort* __restrict__ m1H,  const ushort* __restrict__ m1L,
               const float* __restrict__ c1, const float* __restrict__ bhh,
               const float* __restrict__ lin_w, const float* __restrict__ lin_b,
               float* __restrict__ out, int N, int P){
  __shared__ __align__(16) ushort hb[2][2][64*64];   // [buf][hi/lo][node*64+ch] swizzled
  const int tid  = threadIdx.x;
  const int l    = tid & 63, w = tid >> 6;
  const int lrow = l & 15;
  const int lgrp = l >> 4;
  const int ch   = w*16 + lrow;
  const int nbase = blockIdx.x * 64;

  s16x8 bH[3][2], bL[3][2], mHf[3], mLf[3];
  #pragma unroll
  for(int g=0; g<3; g++){
    int j = g*HH + w*16 + lrow;
    #pragma unroll
    for(int ks=0; ks<2; ks++){
      int k0 = ks*32 + lgrp*8;
      bH[g][ks] = *(const s16x8*)(whhH + j*HH + k0);
      bL[g][ks] = *(const s16x8*)(whhL + j*HH + k0);
    }
    if(lgrp < 2){
      int k0 = lgrp*8;
      mHf[g] = *(const s16x8*)(m1H + j*FF + k0);
      mLf[g] = *(const s16x8*)(m1L + j*FF + k0);
    } else {
      mHf[g] = (s16x8){0,0,0,0,0,0,0,0};
      mLf[g] = (s16x8){0,0,0,0,0,0,0,0};
    }
  }

  const float cbr = c1[ch]      + bhh[ch];
  const float cbz = c1[ch+HH]   + bhh[ch+HH];
  const float c1n = c1[ch+2*HH];
  const float bhn = bhh[ch+2*HH];

  float hreg[16];
  #pragma unroll
  for(int i=0;i<16;i++) hreg[i]=0.f;

  {
    uint* p = (uint*)&hb[0][0][0];
    for(int i=tid; i<4096; i+=256) p[i]=0u;
  }
  __syncthreads();

  for(int t=0; t<TT; t++){
    const int cur = t & 1, nxt = cur ^ 1;
    const ushort* aHt = aggH + (size_t)t*N*FF;
    const ushort* aLt = aggL + (size_t)t*N*FF;

    #pragma unroll
    for(int nt=0; nt<4; nt++){
      s16x8 ahH[2], ahL[2];
      const int r = nt*16 + lrow;
      #pragma unroll
      for(int ks=0; ks<2; ks++){
        int idx = (r*64 + ks*32 + lgrp*8) ^ ((r&7)<<3);
        ahH[ks] = *(const s16x8*)&hb[cur][0][idx];
        ahL[ks] = *(const s16x8*)&hb[cur][1][idx];
      }
      s16x8 agHf = (s16x8){0,0,0,0,0,0,0,0};
      s16x8 agLf = (s16x8){0,0,0,0,0,0,0,0};
      {
        int node = nbase + nt*16 + lrow;
        int nodec = min(node, N-1);
        if(lgrp < 2){
          size_t o = (size_t)nodec*FF + lgrp*8;
          agHf = *(const s16x8*)(aHt + o);
          agLf = *(const s16x8*)(aLt + o);
        }
      }

      f32x4 aR = {0.f,0.f,0.f,0.f}, aZ = {0.f,0.f,0.f,0.f};
      f32x4 aNi= {0.f,0.f,0.f,0.f}, aNh= {0.f,0.f,0.f,0.f};
      #pragma unroll
      for(int ks=0; ks<2; ks++){
        aR = __builtin_amdgcn_mfma_f32_16x16x32_bf16(ahH[ks], bH[0][ks], aR, 0,0,0);
        aR = __builtin_amdgcn_mfma_f32_16x16x32_bf16(ahL[ks], bH[0][ks], aR, 0,0,0);
        aR = __builtin_amdgcn_mfma_f32_16x16x32_bf16(ahH[ks], bL[0][ks], aR, 0,0,0);
        aZ = __builtin_amdgcn_mfma_f32_16x16x32_bf16(ahH[ks], bH[1][ks], aZ, 0,0,0);
        aZ = __builtin_amdgcn_mfma_f32_16x16x32_bf16(ahL[ks], bH[1][ks], aZ, 0,0,0);
        aZ = __builtin_amdgcn_mfma_f32_16x16x32_bf16(ahH[ks], bL[1][ks], aZ, 0,0,0);
        aNh= __builtin_amdgcn_mfma_f32_16x16x32_bf16(ahH[ks], bH[2][ks], aNh,0,0,0);
        aNh= __builtin_amdgcn_mfma_f32_16x16x32_bf16(ahL[ks], bH[2][ks], aNh,0,0,0);
        aNh= __builtin_amdgcn_mfma_f32_16x16x32_bf16(ahH[ks], bL[2][ks], aNh,0,0,0);
      }
      aR  = __builtin_amdgcn_mfma_f32_16x16x32_bf16(agHf, mHf[0], aR, 0,0,0);
      aR  = __builtin_amdgcn_mfma_f32_16x16x32_bf16(agLf, mHf[0], aR, 0,0,0);
      aR  = __builtin_amdgcn_mfma_f32_16x16x32_bf16(agHf, mLf[0], aR, 0,0,0);
      aZ  = __builtin_amdgcn_mfma_f32_16x16x32_bf16(agHf, mHf[1], aZ, 0,0,0);
      aZ  = __builtin_amdgcn_mfma_f32_16x16x32_bf16(agLf, mHf[1], aZ, 0,0,0);
      aZ  = __builtin_amdgcn_mfma_f32_16x16x32_bf16(agHf, mLf[1], aZ, 0,0,0);
      aNi = __builtin_amdgcn_mfma_f32_16x16x32_bf16(agHf, mHf[2], aNi,0,0,0);
      aNi = __builtin_amdgcn_mfma_f32_16x16x32_bf16(agLf, mHf[2], aNi,0,0,0);
      aNi = __builtin_amdgcn_mfma_f32_16x16x32_bf16(agHf, mLf[2], aNi,0,0,0);

      #pragma unroll
      for(int i=0;i<4;i++){
        float r_ = sigmoid_f(aR[i] + cbr);
        float z_ = sigmoid_f(aZ[i] + cbz);
        float nn = tanh_f(aNi[i] + c1n + r_*(aNh[i] + bhn));
        int hidx = nt*4 + i;
        float hp = hreg[hidx];
        float hn = nn + z_*(hp - nn);
        hreg[hidx] = hn;
        int noderow = nt*16 + lgrp*4 + i;
        int idx = (noderow*64 + ch) ^ ((noderow&7)<<3);
        ushort hiw = f2bf(hn);
        hb[nxt][0][idx] = hiw;
        hb[nxt][1][idx] = f2bf(hn - bf2f(hiw));
      }
    }
    __syncthreads();
  }

  // ---- fused linear head ----
  float* hs = (float*)&hb[0][0][0];
  #pragma unroll
  for(int hidx=0; hidx<16; hidx++){
    int nt = hidx >> 2, i = hidx & 3;
    int r = nt*16 + lgrp*4 + i;
    hs[r*64 + ch] = hreg[hidx];
  }
  __syncthreads();
  {
    int r = l;
    int node = nbase + r;
    if(node < N){
      float hv[HH];
      #pragma unroll
      for(int q=0;q<16;q++){
        float4 v = *(const float4*)&hs[r*64 + q*4];
        hv[4*q]=v.x; hv[4*q+1]=v.y; hv[4*q+2]=v.z; hv[4*q+3]=v.w;
      }
      for(int p=w; p<P; p+=4){
        float acc = lin_b[p];
        #pragma unroll
        for(int k=0;k<HH;k++) acc += hv[k]*lin_w[p*HH+k];
        out[(size_t)p*N + node] = acc;
      }
    }
  }
}

extern "C" void kernel_launch(void* const* d_in, const int* in_sizes, int n_in,
                              void* d_out, int out_size, void* d_ws, size_t ws_size,
                              hipStream_t stream){
  const float* x     = (const float*)d_in[0];
  const float* gcn_w = (const float*)d_in[2];
  const float* gcn_b = (const float*)d_in[3];
  const float* w_ih  = (const float*)d_in[4];
  const float* w_hh  = (const float*)d_in[5];
  const float* b_ih  = (const float*)d_in[6];
  const float* b_hh  = (const float*)d_in[7];
  const float* lin_w = (const float*)d_in[8];
  const float* lin_b = (const float*)d_in[9];
  const int*   ei    = (const int*)d_in[10];
  const int E = in_sizes[10]/2;
  const int N = in_sizes[0]/(TT*FF);
  const int P = in_sizes[9];

  char* wsp = (char*)d_ws;
  auto alloc = [&](size_t bytes)->void*{ void* p = wsp; wsp += (bytes + 255) & ~(size_t)255; return p; };
  int*    deg      = (int*)   alloc((size_t)N*4);
  int*    counters = (int*)   alloc((size_t)N*4);
  int*    offsets  = (int*)   alloc((size_t)(N+1)*4);
  float*  dinv     = (float*) alloc((size_t)N*4);
  int2*   csr2     = (int2*)  alloc((size_t)E*8);
  float4* xT       = (float4*)alloc((size_t)N*96*16);
  ushort* aggH     = (ushort*)alloc((size_t)TT*N*FF*2);
  ushort* aggL     = (ushort*)alloc((size_t)TT*N*FF*2);
  ushort* m1H      = (ushort*)alloc((size_t)GG*FF*2);
  ushort* m1L      = (ushort*)alloc((size_t)GG*FF*2);
  float*  c1       = (float*) alloc((size_t)GG*4);
  ushort* whhH     = (ushort*)alloc((size_t)GG*HH*2);
  ushort* whhL     = (ushort*)alloc((size_t)GG*HH*2);

  k_zero<<<(N+255)/256, 256, 0, stream>>>(deg, N);
  k_zero<<<(N+255)/256, 256, 0, stream>>>(counters, N);

  k_deg <<<(E+255)/256, 256, 0, stream>>>(ei, E, deg);
  k_dinv<<<(N+255)/256, 256, 0, stream>>>(deg, dinv, N);
  k_scan<<<1, 1024, 0, stream>>>(deg, offsets, N);
  k_fill<<<(E+255)/256, 256, 0, stream>>>(ei, E, dinv, offsets, counters, csr2);
  k_m1  <<<(GG*FF+GG+255)/256, 256, 0, stream>>>(gcn_w, gcn_b, w_ih, b_ih, m1H, m1L, c1);
  k_split<<<(GG*HH+255)/256, 256, 0, stream>>>(w_hh, whhH, whhL, GG*HH);

  k_xt  <<<(TT*N*4+255)/256, 256, 0, stream>>>((const float4*)x, xT, N);

  k_aggT<<<(N+3)/4, 256, 0, stream>>>(xT, offsets, csr2, dinv, aggH, aggL, N);

  k_gru_all<<<(N+63)/64, 256, 0, stream>>>(aggH, aggL, whhH, whhL, m1H, m1L, c1, b_hh,
                                           lin_w, lin_b, (float*)d_out, N, P);
}

// Round 6
// 680.832 us; speedup vs baseline: 1.3612x; 1.2169x over previous
//
#include <hip/hip_runtime.h>
#include <hip/hip_bf16.h>
#include <hip/hip_fp16.h>

#define TT 24
#define FF 16
#define HH 64
#define GG 192   // 3*HH

typedef __attribute__((ext_vector_type(4))) float f32x4;
typedef __attribute__((ext_vector_type(8))) short s16x8;

__device__ __forceinline__ ushort f2bf(float x){
  union{float f; unsigned u;} c; c.f = x;
  unsigned r = (c.u + 0x7fffu + ((c.u>>16)&1u)) >> 16;
  return (ushort)r;
}
__device__ __forceinline__ float bf2f(ushort h){
  union{unsigned u; float f;} c; c.u = ((unsigned)h)<<16; return c.f;
}
__device__ __forceinline__ float fast_rcp(float x){ return __builtin_amdgcn_rcpf(x); }
__device__ __forceinline__ float sigmoid_f(float x){
  return fast_rcp(1.0f + __expf(-x));
}
__device__ __forceinline__ float tanh_f(float x){
  float e = __expf(-2.0f * fabsf(x));
  float th = (1.0f - e) * fast_rcp(1.0f + e);
  return copysignf(th, x);
}
__device__ __forceinline__ float4 h4tof4(uint2 u){
  __half2 p0 = *(__half2*)&u.x, p1 = *(__half2*)&u.y;
  float2 f0 = __half22float2(p0), f1 = __half22float2(p1);
  return make_float4(f0.x, f0.y, f1.x, f1.y);
}

// ---------------- CSR build ----------------
__global__ void k_zero2(int* __restrict__ a, int* __restrict__ b, int n){
  int i = blockIdx.x*blockDim.x + threadIdx.x;
  if(i<n){ a[i]=0; b[i]=0; }
}

__global__ void k_deg(const int* __restrict__ ei, int E, int* __restrict__ deg){
  int i = blockIdx.x*blockDim.x + threadIdx.x;
  if(i<E) atomicAdd(&deg[ei[E+i]], 1);   // dst = ei[E+i]
}

// exclusive prefix sum of deg -> offsets[0..N]; also dinv = rsqrt(deg+1)
__global__ __launch_bounds__(1024) void k_scan(const int* __restrict__ deg, int* __restrict__ offsets,
                                               float* __restrict__ dinv, int N){
  __shared__ int s[1024];
  int tid = threadIdx.x;
  int CH = (N + 1023) >> 10;
  int lo = tid*CH, hi = min(N, lo+CH);
  int sum=0;
  for(int j=lo;j<hi;j++){
    int d = deg[j];
    dinv[j] = rsqrtf((float)d + 1.0f);
    sum += d;
  }
  s[tid]=sum; __syncthreads();
  for(int o=1;o<1024;o<<=1){
    int v = 0;
    if(tid>=o) v = s[tid-o];
    __syncthreads();
    s[tid] += v;
    __syncthreads();
  }
  int run = s[tid]-sum;
  for(int j=lo;j<hi;j++){ offsets[j]=run; run += deg[j]; }
  if(tid==1023) offsets[N]=s[1023];
}

__global__ void k_fill(const int* __restrict__ ei, int E, const float* __restrict__ dinv,
                       const int* __restrict__ offsets, int* __restrict__ counters,
                       int2* __restrict__ csr2){
  int i = blockIdx.x*blockDim.x + threadIdx.x;
  if(i>=E) return;
  int s = ei[i], d = ei[E+i];
  int slot = offsets[d] + atomicAdd(&counters[d], 1);
  csr2[slot] = make_int2(s, __float_as_int(dinv[s]*dinv[d]));
}

// ---------------- weight prep (merged M1/c1 + w_hh split) ----------------
__global__ void k_prep(const float* __restrict__ gcn_w, const float* __restrict__ gcn_b,
                       const float* __restrict__ w_ih, const float* __restrict__ b_ih,
                       const float* __restrict__ w_hh,
                       ushort* __restrict__ m1H, ushort* __restrict__ m1L, float* __restrict__ c1,
                       ushort* __restrict__ whhH, ushort* __restrict__ whhL){
  int tid = blockIdx.x*blockDim.x + threadIdx.x;
  if(tid < GG*FF){
    int j = tid >> 4, f = tid & 15;
    float s = 0.f;
    for(int k=0;k<HH;k++) s += gcn_w[f*HH+k]*w_ih[j*HH+k];
    ushort h = f2bf(s);
    m1H[tid] = h;
    m1L[tid] = f2bf(s - bf2f(h));
  } else if (tid < GG*FF + GG){
    int j = tid - GG*FF;
    float s = b_ih[j];
    for(int k=0;k<HH;k++) s += gcn_b[k]*w_ih[j*HH+k];
    c1[j] = s;
  }
  if(tid < GG*HH){
    float v = w_hh[tid];
    ushort h = f2bf(v);
    whhH[tid] = h;
    whhL[tid] = f2bf(v - bf2f(h));
  }
}

// ---------------- transpose+convert: x[t][n][f] fp32 -> xTh[n][t*16+f] fp16 ----------------
// block = 256, 16 nodes per block; LDS staged, both global sides coalesced.
__global__ __launch_bounds__(256)
void k_xt2(const float* __restrict__ x, ushort* __restrict__ xTh, int N){
  __shared__ ushort tile[16][392];   // 384 + 8 pad (stride 196 dwords, conflict-free)
  const int nbase = blockIdx.x * 16;
  const int tid = threadIdx.x;
  const int nd = tid >> 4, f = tid & 15;
  const int n = nbase + nd;
  for(int t=0; t<TT; t++){
    float v = (n < N) ? x[((size_t)t*N + n)*FF + f] : 0.f;
    tile[nd][t*16 + f] = __half_as_ushort(__float2half(v));
  }
  __syncthreads();
  uint* xo = (uint*)xTh;
  for(int i = tid; i < 16*192; i += 256){
    int d = i / 192, pos = i - d*192;
    int nn = nbase + d;
    if(nn < N) xo[(size_t)nn*192 + pos] = *(uint*)&tile[d][pos*2];
  }
}

// ---------------- aggregation v6: wave per dst node, fp16 rows, all 24 t at once ----------------
// xTh row per node = 768 B = 96 x uint2(4 halfs). lane: half = l>>5 (edge slot), lh = l&31.
// Half-wave reads one edge's row as 3 coalesced 8 B loads (units lh, lh+32, lh+64).
__global__ __launch_bounds__(256)
void k_aggTh(const ushort* __restrict__ xTh, const int* __restrict__ offsets,
             const int2* __restrict__ csr2, const float* __restrict__ dinv,
             ushort* __restrict__ aggH, ushort* __restrict__ aggL, int N){
  int wid = (blockIdx.x*blockDim.x + threadIdx.x) >> 6;
  if(wid >= N) return;
  const int l = threadIdx.x & 63;
  const int half = l >> 5, lh = l & 31;
  const int n = wid;

  float4 a0 = make_float4(0.f,0.f,0.f,0.f);
  float4 a1 = make_float4(0.f,0.f,0.f,0.f);
  float4 a2 = make_float4(0.f,0.f,0.f,0.f);

  const int lo = offsets[n], hi = offsets[n+1];
  for(int j = lo; j < hi; j += 4){
    int ja = j + half;
    int jb = j + 2 + half;
    bool okA = ja < hi, okB = jb < hi;
    int2 cA = csr2[okA ? ja : lo];
    int2 cB = csr2[okB ? jb : lo];
    float wA = okA ? __int_as_float(cA.y) : 0.f;
    float wB = okB ? __int_as_float(cB.y) : 0.f;
    const uint2* rA = (const uint2*)(xTh + (size_t)cA.x*384) + lh;
    const uint2* rB = (const uint2*)(xTh + (size_t)cB.x*384) + lh;
    uint2 uA0 = rA[0], uA1 = rA[32], uA2 = rA[64];
    uint2 uB0 = rB[0], uB1 = rB[32], uB2 = rB[64];
    float4 vA0 = h4tof4(uA0), vA1 = h4tof4(uA1), vA2 = h4tof4(uA2);
    float4 vB0 = h4tof4(uB0), vB1 = h4tof4(uB1), vB2 = h4tof4(uB2);
    a0.x += wA*vA0.x; a0.y += wA*vA0.y; a0.z += wA*vA0.z; a0.w += wA*vA0.w;
    a1.x += wA*vA1.x; a1.y += wA*vA1.y; a1.z += wA*vA1.z; a1.w += wA*vA1.w;
    a2.x += wA*vA2.x; a2.y += wA*vA2.y; a2.z += wA*vA2.z; a2.w += wA*vA2.w;
    a0.x += wB*vB0.x; a0.y += wB*vB0.y; a0.z += wB*vB0.z; a0.w += wB*vB0.w;
    a1.x += wB*vB1.x; a1.y += wB*vB1.y; a1.z += wB*vB1.z; a1.w += wB*vB1.w;
    a2.x += wB*vB2.x; a2.y += wB*vB2.y; a2.z += wB*vB2.z; a2.w += wB*vB2.w;
  }
  // reduce across the two halves
  a0.x += __shfl_xor(a0.x, 32, 64); a0.y += __shfl_xor(a0.y, 32, 64);
  a0.z += __shfl_xor(a0.z, 32, 64); a0.w += __shfl_xor(a0.w, 32, 64);
  a1.x += __shfl_xor(a1.x, 32, 64); a1.y += __shfl_xor(a1.y, 32, 64);
  a1.z += __shfl_xor(a1.z, 32, 64); a1.w += __shfl_xor(a1.w, 32, 64);
  a2.x += __shfl_xor(a2.x, 32, 64); a2.y += __shfl_xor(a2.y, 32, 64);
  a2.z += __shfl_xor(a2.z, 32, 64); a2.w += __shfl_xor(a2.w, 32, 64);

  if(half == 0){
    float sn = dinv[n]; sn *= sn;
    const uint2* rS = (const uint2*)(xTh + (size_t)n*384) + lh;
    float4 s0 = h4tof4(rS[0]), s1 = h4tof4(rS[32]), s2 = h4tof4(rS[64]);
    a0.x += sn*s0.x; a0.y += sn*s0.y; a0.z += sn*s0.z; a0.w += sn*s0.w;
    a1.x += sn*s1.x; a1.y += sn*s1.y; a1.z += sn*s1.z; a1.w += sn*s1.w;
    a2.x += sn*s2.x; a2.y += sn*s2.y; a2.z += sn*s2.z; a2.w += sn*s2.w;
    float4 acc[3] = {a0, a1, a2};
    #pragma unroll
    for(int k=0;k<3;k++){
      int u  = lh + k*32;          // u = t*4 + f4
      int t  = u >> 2, f4 = u & 3;
      size_t o = ((size_t)t*N + n)*FF + f4*4;
      float4 a = acc[k];
      ushort4 h, lw;
      h.x = f2bf(a.x); lw.x = f2bf(a.x - bf2f(h.x));
      h.y = f2bf(a.y); lw.y = f2bf(a.y - bf2f(h.y));
      h.z = f2bf(a.z); lw.z = f2bf(a.z - bf2f(h.z));
      h.w = f2bf(a.w); lw.w = f2bf(a.w - bf2f(h.w));
      *(ushort4*)(aggH + o) = h;
      *(ushort4*)(aggL + o) = lw;
    }
  }
}

// ---------------- persistent MFMA GRU over all 24 steps + fused linear head ----------------
__global__ __launch_bounds__(256, 2)
void k_gru_all(const ushort* __restrict__ aggH, const ushort* __restrict__ aggL,
               const ushort* __restrict__ whhH, const ushort* __restrict__ whhL,
               const ushort* __restrict__ m1H,  const ushort* __restrict__ m1L,
               const float* __restrict__ c1, const float* __restrict__ bhh,
               const float* __restrict__ lin_w, const float* __restrict__ lin_b,
               float* __restrict__ out, int N, int P){
  __shared__ __align__(16) ushort hb[2][2][64*64];   // [buf][hi/lo][node*64+ch] swizzled
  const int tid  = threadIdx.x;
  const int l    = tid & 63, w = tid >> 6;
  const int lrow = l & 15;
  const int lgrp = l >> 4;
  const int ch   = w*16 + lrow;
  const int nbase = blockIdx.x * 64;

  s16x8 bH[3][2], bL[3][2], mHf[3], mLf[3];
  #pragma unroll
  for(int g=0; g<3; g++){
    int j = g*HH + w*16 + lrow;
    #pragma unroll
    for(int ks=0; ks<2; ks++){
      int k0 = ks*32 + lgrp*8;
      bH[g][ks] = *(const s16x8*)(whhH + j*HH + k0);
      bL[g][ks] = *(const s16x8*)(whhL + j*HH + k0);
    }
    if(lgrp < 2){
      int k0 = lgrp*8;
      mHf[g] = *(const s16x8*)(m1H + j*FF + k0);
      mLf[g] = *(const s16x8*)(m1L + j*FF + k0);
    } else {
      mHf[g] = (s16x8){0,0,0,0,0,0,0,0};
      mLf[g] = (s16x8){0,0,0,0,0,0,0,0};
    }
  }

  const float cbr = c1[ch]      + bhh[ch];
  const float cbz = c1[ch+HH]   + bhh[ch+HH];
  const float c1n = c1[ch+2*HH];
  const float bhn = bhh[ch+2*HH];

  float hreg[16];
  #pragma unroll
  for(int i=0;i<16;i++) hreg[i]=0.f;

  {
    uint* p = (uint*)&hb[0][0][0];
    for(int i=tid; i<4096; i+=256) p[i]=0u;
  }
  __syncthreads();

  for(int t=0; t<TT; t++){
    const int cur = t & 1, nxt = cur ^ 1;
    const ushort* aHt = aggH + (size_t)t*N*FF;
    const ushort* aLt = aggL + (size_t)t*N*FF;

    #pragma unroll
    for(int nt=0; nt<4; nt++){
      s16x8 ahH[2], ahL[2];
      const int r = nt*16 + lrow;
      #pragma unroll
      for(int ks=0; ks<2; ks++){
        int idx = (r*64 + ks*32 + lgrp*8) ^ ((r&7)<<3);
        ahH[ks] = *(const s16x8*)&hb[cur][0][idx];
        ahL[ks] = *(const s16x8*)&hb[cur][1][idx];
      }
      s16x8 agHf = (s16x8){0,0,0,0,0,0,0,0};
      s16x8 agLf = (s16x8){0,0,0,0,0,0,0,0};
      {
        int node = nbase + nt*16 + lrow;
        int nodec = min(node, N-1);
        if(lgrp < 2){
          size_t o = (size_t)nodec*FF + lgrp*8;
          agHf = *(const s16x8*)(aHt + o);
          agLf = *(const s16x8*)(aLt + o);
        }
      }

      f32x4 aR = {0.f,0.f,0.f,0.f}, aZ = {0.f,0.f,0.f,0.f};
      f32x4 aNi= {0.f,0.f,0.f,0.f}, aNh= {0.f,0.f,0.f,0.f};
      #pragma unroll
      for(int ks=0; ks<2; ks++){
        aR = __builtin_amdgcn_mfma_f32_16x16x32_bf16(ahH[ks], bH[0][ks], aR, 0,0,0);
        aR = __builtin_amdgcn_mfma_f32_16x16x32_bf16(ahL[ks], bH[0][ks], aR, 0,0,0);
        aR = __builtin_amdgcn_mfma_f32_16x16x32_bf16(ahH[ks], bL[0][ks], aR, 0,0,0);
        aZ = __builtin_amdgcn_mfma_f32_16x16x32_bf16(ahH[ks], bH[1][ks], aZ, 0,0,0);
        aZ = __builtin_amdgcn_mfma_f32_16x16x32_bf16(ahL[ks], bH[1][ks], aZ, 0,0,0);
        aZ = __builtin_amdgcn_mfma_f32_16x16x32_bf16(ahH[ks], bL[1][ks], aZ, 0,0,0);
        aNh= __builtin_amdgcn_mfma_f32_16x16x32_bf16(ahH[ks], bH[2][ks], aNh,0,0,0);
        aNh= __builtin_amdgcn_mfma_f32_16x16x32_bf16(ahL[ks], bH[2][ks], aNh,0,0,0);
        aNh= __builtin_amdgcn_mfma_f32_16x16x32_bf16(ahH[ks], bL[2][ks], aNh,0,0,0);
      }
      aR  = __builtin_amdgcn_mfma_f32_16x16x32_bf16(agHf, mHf[0], aR, 0,0,0);
      aR  = __builtin_amdgcn_mfma_f32_16x16x32_bf16(agLf, mHf[0], aR, 0,0,0);
      aR  = __builtin_amdgcn_mfma_f32_16x16x32_bf16(agHf, mLf[0], aR, 0,0,0);
      aZ  = __builtin_amdgcn_mfma_f32_16x16x32_bf16(agHf, mHf[1], aZ, 0,0,0);
      aZ  = __builtin_amdgcn_mfma_f32_16x16x32_bf16(agLf, mHf[1], aZ, 0,0,0);
      aZ  = __builtin_amdgcn_mfma_f32_16x16x32_bf16(agHf, mLf[1], aZ, 0,0,0);
      aNi = __builtin_amdgcn_mfma_f32_16x16x32_bf16(agHf, mHf[2], aNi,0,0,0);
      aNi = __builtin_amdgcn_mfma_f32_16x16x32_bf16(agLf, mHf[2], aNi,0,0,0);
      aNi = __builtin_amdgcn_mfma_f32_16x16x32_bf16(agHf, mLf[2], aNi,0,0,0);

      #pragma unroll
      for(int i=0;i<4;i++){
        float r_ = sigmoid_f(aR[i] + cbr);
        float z_ = sigmoid_f(aZ[i] + cbz);
        float nn = tanh_f(aNi[i] + c1n + r_*(aNh[i] + bhn));
        int hidx = nt*4 + i;
        float hp = hreg[hidx];
        float hn = nn + z_*(hp - nn);
        hreg[hidx] = hn;
        int noderow = nt*16 + lgrp*4 + i;
        int idx = (noderow*64 + ch) ^ ((noderow&7)<<3);
        ushort hiw = f2bf(hn);
        hb[nxt][0][idx] = hiw;
        hb[nxt][1][idx] = f2bf(hn - bf2f(hiw));
      }
    }
    __syncthreads();
  }

  // ---- fused linear head ----
  float* hs = (float*)&hb[0][0][0];
  #pragma unroll
  for(int hidx=0; hidx<16; hidx++){
    int nt = hidx >> 2, i = hidx & 3;
    int r = nt*16 + lgrp*4 + i;
    hs[r*64 + ch] = hreg[hidx];
  }
  __syncthreads();
  {
    int r = l;
    int node = nbase + r;
    if(node < N){
      float hv[HH];
      #pragma unroll
      for(int q=0;q<16;q++){
        float4 v = *(const float4*)&hs[r*64 + q*4];
        hv[4*q]=v.x; hv[4*q+1]=v.y; hv[4*q+2]=v.z; hv[4*q+3]=v.w;
      }
      for(int p=w; p<P; p+=4){
        float acc = lin_b[p];
        #pragma unroll
        for(int k=0;k<HH;k++) acc += hv[k]*lin_w[p*HH+k];
        out[(size_t)p*N + node] = acc;
      }
    }
  }
}

extern "C" void kernel_launch(void* const* d_in, const int* in_sizes, int n_in,
                              void* d_out, int out_size, void* d_ws, size_t ws_size,
                              hipStream_t stream){
  const float* x     = (const float*)d_in[0];
  const float* gcn_w = (const float*)d_in[2];
  const float* gcn_b = (const float*)d_in[3];
  const float* w_ih  = (const float*)d_in[4];
  const float* w_hh  = (const float*)d_in[5];
  const float* b_ih  = (const float*)d_in[6];
  const float* b_hh  = (const float*)d_in[7];
  const float* lin_w = (const float*)d_in[8];
  const float* lin_b = (const float*)d_in[9];
  const int*   ei    = (const int*)d_in[10];
  const int E = in_sizes[10]/2;
  const int N = in_sizes[0]/(TT*FF);
  const int P = in_sizes[9];

  char* wsp = (char*)d_ws;
  auto alloc = [&](size_t bytes)->void*{ void* p = wsp; wsp += (bytes + 255) & ~(size_t)255; return p; };
  int*    deg      = (int*)   alloc((size_t)N*4);
  int*    counters = (int*)   alloc((size_t)N*4);
  int*    offsets  = (int*)   alloc((size_t)(N+1)*4);
  float*  dinv     = (float*) alloc((size_t)N*4);
  int2*   csr2     = (int2*)  alloc((size_t)E*8);
  ushort* xTh      = (ushort*)alloc((size_t)N*384*2);
  ushort* aggH     = (ushort*)alloc((size_t)TT*N*FF*2);
  ushort* aggL     = (ushort*)alloc((size_t)TT*N*FF*2);
  ushort* m1H      = (ushort*)alloc((size_t)GG*FF*2);
  ushort* m1L      = (ushort*)alloc((size_t)GG*FF*2);
  float*  c1       = (float*) alloc((size_t)GG*4);
  ushort* whhH     = (ushort*)alloc((size_t)GG*HH*2);
  ushort* whhL     = (ushort*)alloc((size_t)GG*HH*2);

  k_zero2<<<(N+255)/256, 256, 0, stream>>>(deg, counters, N);
  k_deg  <<<(E+255)/256, 256, 0, stream>>>(ei, E, deg);
  k_scan <<<1, 1024, 0, stream>>>(deg, offsets, dinv, N);
  k_fill <<<(E+255)/256, 256, 0, stream>>>(ei, E, dinv, offsets, counters, csr2);
  k_prep <<<(GG*HH+255)/256, 256, 0, stream>>>(gcn_w, gcn_b, w_ih, b_ih, w_hh,
                                               m1H, m1L, c1, whhH, whhL);
  k_xt2  <<<(N+15)/16, 256, 0, stream>>>(x, xTh, N);
  k_aggTh<<<(N+3)/4, 256, 0, stream>>>(xTh, offsets, csr2, dinv, aggH, aggL, N);
  k_gru_all<<<(N+63)/64, 256, 0, stream>>>(aggH, aggL, whhH, whhL, m1H, m1L, c1, b_hh,
                                           lin_w, lin_b, (float*)d_out, N, P);
}